// Round 1
// baseline (288.384 us; speedup 1.0000x reference)
//
#include <hip/hip_runtime.h>
#include <float.h>
#include <math.h>

#define NPTS 16384
#define HDIM 256
#define TS   2048   // knn LDS tile (points)

__device__ __forceinline__ float silu_f(float z) {
    return z / (1.0f + __expf(-z));
}

// ---------------------------------------------------------------------------
// Kernel 1: for each row, mean of the 6 nearest-neighbor distances
// (ranks 2..7 ascending, i.e. top-(k+1) smallest minus the self/smallest).
// One wave per row, 4 rows per 256-thread block.
// Per-lane sorted top-7 of d^2, wave-wide cutoff prune, 7-round wave merge.
// ---------------------------------------------------------------------------
__global__ __launch_bounds__(256) void knn_kernel(const float* __restrict__ xyf,
                                                  float* __restrict__ md) {
    __shared__ float2 tile[TS];
    const float2* xy = (const float2*)xyf;
    const int lane = threadIdx.x & 63;
    const int wv   = threadIdx.x >> 6;
    const int row  = blockIdx.x * 4 + wv;

    const float2 q = xy[row];
    float s0 = FLT_MAX, s1 = FLT_MAX, s2 = FLT_MAX, s3 = FLT_MAX,
          s4 = FLT_MAX, s5 = FLT_MAX, s6 = FLT_MAX;

    for (int base = 0; base < NPTS; base += TS) {
        __syncthreads();
        for (int i = threadIdx.x; i < TS; i += 256) tile[i] = xy[base + i];
        __syncthreads();

        // wave-wide prune cutoff: C = min over lanes of s6 (>= global 7th seen)
        float C = s6;
        #pragma unroll
        for (int o = 32; o; o >>= 1) C = fminf(C, __shfl_xor(C, o, 64));

        for (int i = lane; i < TS; i += 64) {
            const float2 p = tile[i];
            const float dx = q.x - p.x;
            const float dy = q.y - p.y;
            const float d  = fmaf(dx, dx, dy * dy);
            if (d < C && d < s6) {
                s6 = d;
                float t;
                if (s6 < s5) { t = s5; s5 = s6; s6 = t; }
                if (s5 < s4) { t = s4; s4 = s5; s5 = t; }
                if (s4 < s3) { t = s3; s3 = s4; s4 = t; }
                if (s3 < s2) { t = s2; s2 = s3; s3 = t; }
                if (s2 < s1) { t = s1; s1 = s2; s2 = t; }
                if (s1 < s0) { t = s0; s0 = s1; s1 = t; }
            }
        }
    }

    // merge the 64 per-lane sorted lists: pop global min 7 times
    float sum = 0.0f;
    #pragma unroll
    for (int r = 0; r < 7; ++r) {
        const float v = s0;
        float m = v;
        #pragma unroll
        for (int o = 32; o; o >>= 1) m = fminf(m, __shfl_xor(m, o, 64));
        const unsigned long long msk = __ballot(v == m);
        if (lane == (__ffsll(msk) - 1)) {
            s0 = s1; s1 = s2; s2 = s3; s3 = s4; s4 = s5; s5 = s6; s6 = FLT_MAX;
        }
        if (r > 0) sum += sqrtf(fmaxf(m, 1e-12f));
    }
    if (lane == 0) md[row] = sum * (1.0f / 6.0f);
}

// ---------------------------------------------------------------------------
// Kernel 2: fused  out = silu(x@W1+b1)@W2 + b2 + silu(md@Wd1+bd1)@Wd2 + bd2
// 32 points x 256 cols per block (256 threads). Thread = 4 cols x 8 points,
// 32 fp32 accumulators. h1 / g staged transposed in LDS (stride 36 floats:
// 16B-aligned rows, no 64-way write conflict; main-loop reads are wave-uniform
// broadcasts).
// ---------------------------------------------------------------------------
__global__ __launch_bounds__(256) void mlp_kernel(
        const float* __restrict__ xyf,
        const float* __restrict__ W1,  const float* __restrict__ b1,
        const float* __restrict__ W2,  const float* __restrict__ b2,
        const float* __restrict__ Wd1, const float* __restrict__ bd1,
        const float* __restrict__ Wd2, const float* __restrict__ bd2,
        const float* __restrict__ md,  float* __restrict__ out) {
    __shared__ __align__(16) float hT[256 * 36];
    __shared__ float2 sxy[32];
    __shared__ float  smd[32];

    const int tid   = threadIdx.x;
    const int pbase = blockIdx.x * 32;

    if (tid < 32) {
        sxy[tid] = ((const float2*)xyf)[pbase + tid];
        smd[tid] = md[pbase + tid];
    }
    __syncthreads();

    // phase A: h1[k][p] = silu(x[p]@W1[:,k] + b1[k]), k = tid
    {
        const int k = tid;
        const float w0 = W1[k], w1 = W1[HDIM + k], b = b1[k];
        #pragma unroll 8
        for (int p = 0; p < 32; ++p) {
            const float2 xp = sxy[p];
            const float z = fmaf(xp.x, w0, fmaf(xp.y, w1, b));
            hT[k * 36 + p] = silu_f(z);
        }
    }
    __syncthreads();

    const int tx = tid & 63;
    const int ty = tid >> 6;
    const int c0 = tx * 4;
    const int p0 = ty * 8;

    float acc[8][4];
    #pragma unroll
    for (int p = 0; p < 8; ++p)
        #pragma unroll
        for (int c = 0; c < 4; ++c) acc[p][c] = 0.0f;

    // main GEMM: acc += h1 @ W2
    #pragma unroll 2
    for (int k = 0; k < 256; ++k) {
        const float4 w  = *(const float4*)(W2 + k * HDIM + c0);
        const float4 a0 = *(const float4*)(&hT[k * 36 + p0]);
        const float4 a1 = *(const float4*)(&hT[k * 36 + p0 + 4]);
        const float a[8] = {a0.x, a0.y, a0.z, a0.w, a1.x, a1.y, a1.z, a1.w};
        #pragma unroll
        for (int p = 0; p < 8; ++p) {
            acc[p][0] = fmaf(a[p], w.x, acc[p][0]);
            acc[p][1] = fmaf(a[p], w.y, acc[p][1]);
            acc[p][2] = fmaf(a[p], w.z, acc[p][2]);
            acc[p][3] = fmaf(a[p], w.w, acc[p][3]);
        }
    }
    __syncthreads();

    // phase B: g[j][p] = silu(md[p]*Wd1[j] + bd1[j]), j = tid < 128
    if (tid < 128) {
        const int j = tid;
        const float wd = Wd1[j], bd = bd1[j];
        #pragma unroll 8
        for (int p = 0; p < 32; ++p) {
            const float z = fmaf(smd[p], wd, bd);
            hT[j * 36 + p] = silu_f(z);
        }
    }
    __syncthreads();

    // acc += g @ Wd2
    #pragma unroll 2
    for (int k = 0; k < 128; ++k) {
        const float4 w  = *(const float4*)(Wd2 + k * HDIM + c0);
        const float4 a0 = *(const float4*)(&hT[k * 36 + p0]);
        const float4 a1 = *(const float4*)(&hT[k * 36 + p0 + 4]);
        const float a[8] = {a0.x, a0.y, a0.z, a0.w, a1.x, a1.y, a1.z, a1.w};
        #pragma unroll
        for (int p = 0; p < 8; ++p) {
            acc[p][0] = fmaf(a[p], w.x, acc[p][0]);
            acc[p][1] = fmaf(a[p], w.y, acc[p][1]);
            acc[p][2] = fmaf(a[p], w.z, acc[p][2]);
            acc[p][3] = fmaf(a[p], w.w, acc[p][3]);
        }
    }

    // epilogue: + b2 + bd2, coalesced float4 stores
    const float4 v2 = *(const float4*)(b2 + c0);
    const float4 vd = *(const float4*)(bd2 + c0);
    #pragma unroll
    for (int p = 0; p < 8; ++p) {
        float4 o;
        o.x = acc[p][0] + v2.x + vd.x;
        o.y = acc[p][1] + v2.y + vd.y;
        o.z = acc[p][2] + v2.z + vd.z;
        o.w = acc[p][3] + v2.w + vd.w;
        *(float4*)(out + (size_t)(pbase + p0 + p) * HDIM + c0) = o;
    }
}

extern "C" void kernel_launch(void* const* d_in, const int* in_sizes, int n_in,
                              void* d_out, int out_size, void* d_ws, size_t ws_size,
                              hipStream_t stream) {
    const float* xy  = (const float*)d_in[0];
    const float* W1  = (const float*)d_in[1];
    const float* b1  = (const float*)d_in[2];
    const float* W2  = (const float*)d_in[3];
    const float* b2  = (const float*)d_in[4];
    const float* Wd1 = (const float*)d_in[5];
    const float* bd1 = (const float*)d_in[6];
    const float* Wd2 = (const float*)d_in[7];
    const float* bd2 = (const float*)d_in[8];
    // d_in[9] is k == 6 (fixed by setup_inputs; kernels hard-code top-7)
    float* out = (float*)d_out;
    float* md  = (float*)d_ws;  // 16384 floats of scratch for mean distances

    knn_kernel<<<NPTS / 4, 256, 0, stream>>>(xy, md);
    mlp_kernel<<<NPTS / 32, 256, 0, stream>>>(xy, W1, b1, W2, b2,
                                              Wd1, bd1, Wd2, bd2, md, out);
}

// Round 2
// 216.585 us; speedup vs baseline: 1.3315x; 1.3315x over previous
//
#include <hip/hip_runtime.h>
#include <float.h>
#include <math.h>

#define NPTS 16384
#define HDIM 256
#define TS   2048   // knn LDS tile (points); TS/2 float4 = 16 KB

__device__ __forceinline__ float silu_f(float z) {
    return z / (1.0f + __expf(-z));
}

// ---------------------------------------------------------------------------
// Kernel 1: mean of 6-NN distances per row (ranks 2..7 of sorted distances).
// One wave per row, 4 rows/block. WAVE-SHARED sorted top-7 of d^2 replicated
// in every lane's registers (wave-uniform). Scan: 4 points/lane/iter, one
// v_cmp + scalar branch per 256 pairs. Inserts: rare scalar-branched loop,
// ballot -> ffs -> readlane -> 12-op uniform min/max insert. s6 is the exact
// running 7th-smallest => optimal pruning, and no cross-lane merge at the end.
// ---------------------------------------------------------------------------
__global__ __launch_bounds__(256) void knn_kernel(const float* __restrict__ xyf,
                                                  float* __restrict__ md) {
    __shared__ float4 tile4[TS / 2];
    const float4* xy4 = (const float4*)xyf;
    const float2* xy2 = (const float2*)xyf;
    const int lane = threadIdx.x & 63;
    const int wv   = threadIdx.x >> 6;
    const int row  = blockIdx.x * 4 + wv;

    const float2 q = xy2[row];
    float s0 = FLT_MAX, s1 = FLT_MAX, s2 = FLT_MAX, s3 = FLT_MAX,
          s4 = FLT_MAX, s5 = FLT_MAX, s6 = FLT_MAX;

    for (int t0 = 0; t0 < NPTS / 2; t0 += TS / 2) {
        __syncthreads();
        for (int i = threadIdx.x; i < TS / 2; i += 256) tile4[i] = xy4[t0 + i];
        __syncthreads();

        #pragma unroll
        for (int jj = 0; jj < TS / 2; jj += 128) {
            const int j0 = jj + 2 * lane;
            const float4 A = tile4[j0];
            const float4 B = tile4[j0 + 1];
            float dx, dy;
            dx = q.x - A.x; dy = q.y - A.y; float d0 = fmaf(dx, dx, dy * dy);
            dx = q.x - A.z; dy = q.y - A.w; float d1 = fmaf(dx, dx, dy * dy);
            dx = q.x - B.x; dy = q.y - B.y; float d2 = fmaf(dx, dx, dy * dy);
            dx = q.x - B.z; dy = q.y - B.w; float d3 = fmaf(dx, dx, dy * dy);
            float mv = fminf(fminf(d0, d1), fminf(d2, d3));

            unsigned long long m = __ballot(mv < s6);
            while (m) {                              // rare after warmup
                const int L  = __ffsll(m) - 1;
                const float v = __shfl(mv, L);       // readlane -> wave-uniform
                // uniform sorted insert of v (< s6) into s0..s6, drop old s6
                s6 = fmaxf(s5, v);
                s5 = fmaxf(s4, fminf(s5, v));
                s4 = fmaxf(s3, fminf(s4, v));
                s3 = fmaxf(s2, fminf(s3, v));
                s2 = fmaxf(s1, fminf(s2, v));
                s1 = fmaxf(s0, fminf(s1, v));
                s0 = fminf(s0, v);
                if (lane == L) {                     // consume the candidate
                    if      (d0 == mv) d0 = FLT_MAX;
                    else if (d1 == mv) d1 = FLT_MAX;
                    else if (d2 == mv) d2 = FLT_MAX;
                    else               d3 = FLT_MAX;
                    mv = fminf(fminf(d0, d1), fminf(d2, d3));
                }
                m = __ballot(mv < s6);
            }
        }
    }

    if (lane == 0) {
        const float sum = sqrtf(fmaxf(s1, 1e-12f)) + sqrtf(fmaxf(s2, 1e-12f)) +
                          sqrtf(fmaxf(s3, 1e-12f)) + sqrtf(fmaxf(s4, 1e-12f)) +
                          sqrtf(fmaxf(s5, 1e-12f)) + sqrtf(fmaxf(s6, 1e-12f));
        md[row] = sum * (1.0f / 6.0f);
    }
}

// ---------------------------------------------------------------------------
// Kernel 2: fused  out = silu(x@W1+b1)@W2 + b2 + silu(md@Wd1+bd1)@Wd2 + bd2
// 32 points x 256 cols per block (256 threads), thread = 4 cols x 8 points.
// W2/Wd2 row loads are software-pipelined depth-2 to break the per-iteration
// L2-load -> use dependency at ~4 waves/SIMD occupancy.
// ---------------------------------------------------------------------------
__global__ __launch_bounds__(256) void mlp_kernel(
        const float* __restrict__ xyf,
        const float* __restrict__ W1,  const float* __restrict__ b1,
        const float* __restrict__ W2,  const float* __restrict__ b2,
        const float* __restrict__ Wd1, const float* __restrict__ bd1,
        const float* __restrict__ Wd2, const float* __restrict__ bd2,
        const float* __restrict__ md,  float* __restrict__ out) {
    __shared__ __align__(16) float hT[256 * 36];
    __shared__ float2 sxy[32];
    __shared__ float  smd[32];

    const int tid   = threadIdx.x;
    const int pbase = blockIdx.x * 32;

    if (tid < 32) {
        sxy[tid] = ((const float2*)xyf)[pbase + tid];
        smd[tid] = md[pbase + tid];
    }
    __syncthreads();

    // phase A: h1[k][p] = silu(x[p]@W1[:,k] + b1[k]), k = tid
    {
        const int k = tid;
        const float w0 = W1[k], w1 = W1[HDIM + k], b = b1[k];
        #pragma unroll 8
        for (int p = 0; p < 32; ++p) {
            const float2 xp = sxy[p];
            const float z = fmaf(xp.x, w0, fmaf(xp.y, w1, b));
            hT[k * 36 + p] = silu_f(z);
        }
    }
    __syncthreads();

    const int tx = tid & 63;
    const int ty = tid >> 6;
    const int c0 = tx * 4;
    const int p0 = ty * 8;

    float acc[8][4];
    #pragma unroll
    for (int p = 0; p < 8; ++p)
        #pragma unroll
        for (int c = 0; c < 4; ++c) acc[p][c] = 0.0f;

    // main GEMM: acc += h1 @ W2, depth-2 pipelined w loads
    {
        const float* W2c = W2 + c0;
        float4 wa = *(const float4*)(W2c);
        float4 wb = *(const float4*)(W2c + HDIM);
        #pragma unroll 2
        for (int k = 0; k < 256; k += 2) {
            const int kn = (k + 2 < 256) ? (k + 2) : 254;   // safe prefetch
            const float4 wc = *(const float4*)(W2c + kn * HDIM);
            const float4 wd = *(const float4*)(W2c + kn * HDIM + HDIM);
            const float4 a0 = *(const float4*)(&hT[k * 36 + p0]);
            const float4 a1 = *(const float4*)(&hT[k * 36 + p0 + 4]);
            const float4 a2 = *(const float4*)(&hT[(k + 1) * 36 + p0]);
            const float4 a3 = *(const float4*)(&hT[(k + 1) * 36 + p0 + 4]);
            const float ak[8] = {a0.x, a0.y, a0.z, a0.w, a1.x, a1.y, a1.z, a1.w};
            const float al[8] = {a2.x, a2.y, a2.z, a2.w, a3.x, a3.y, a3.z, a3.w};
            #pragma unroll
            for (int p = 0; p < 8; ++p) {
                acc[p][0] = fmaf(ak[p], wa.x, acc[p][0]);
                acc[p][1] = fmaf(ak[p], wa.y, acc[p][1]);
                acc[p][2] = fmaf(ak[p], wa.z, acc[p][2]);
                acc[p][3] = fmaf(ak[p], wa.w, acc[p][3]);
            }
            #pragma unroll
            for (int p = 0; p < 8; ++p) {
                acc[p][0] = fmaf(al[p], wb.x, acc[p][0]);
                acc[p][1] = fmaf(al[p], wb.y, acc[p][1]);
                acc[p][2] = fmaf(al[p], wb.z, acc[p][2]);
                acc[p][3] = fmaf(al[p], wb.w, acc[p][3]);
            }
            wa = wc; wb = wd;
        }
    }
    __syncthreads();

    // phase B: g[j][p] = silu(md[p]*Wd1[j] + bd1[j]), j = tid < 128
    if (tid < 128) {
        const int j = tid;
        const float wd = Wd1[j], bd = bd1[j];
        #pragma unroll 8
        for (int p = 0; p < 32; ++p) {
            const float z = fmaf(smd[p], wd, bd);
            hT[j * 36 + p] = silu_f(z);
        }
    }
    __syncthreads();

    // acc += g @ Wd2, depth-2 pipelined
    {
        const float* Wdc = Wd2 + c0;
        float4 wa = *(const float4*)(Wdc);
        float4 wb = *(const float4*)(Wdc + HDIM);
        #pragma unroll 2
        for (int k = 0; k < 128; k += 2) {
            const int kn = (k + 2 < 128) ? (k + 2) : 126;
            const float4 wc = *(const float4*)(Wdc + kn * HDIM);
            const float4 wd = *(const float4*)(Wdc + kn * HDIM + HDIM);
            const float4 a0 = *(const float4*)(&hT[k * 36 + p0]);
            const float4 a1 = *(const float4*)(&hT[k * 36 + p0 + 4]);
            const float4 a2 = *(const float4*)(&hT[(k + 1) * 36 + p0]);
            const float4 a3 = *(const float4*)(&hT[(k + 1) * 36 + p0 + 4]);
            const float ak[8] = {a0.x, a0.y, a0.z, a0.w, a1.x, a1.y, a1.z, a1.w};
            const float al[8] = {a2.x, a2.y, a2.z, a2.w, a3.x, a3.y, a3.z, a3.w};
            #pragma unroll
            for (int p = 0; p < 8; ++p) {
                acc[p][0] = fmaf(ak[p], wa.x, acc[p][0]);
                acc[p][1] = fmaf(ak[p], wa.y, acc[p][1]);
                acc[p][2] = fmaf(ak[p], wa.z, acc[p][2]);
                acc[p][3] = fmaf(ak[p], wa.w, acc[p][3]);
            }
            #pragma unroll
            for (int p = 0; p < 8; ++p) {
                acc[p][0] = fmaf(al[p], wb.x, acc[p][0]);
                acc[p][1] = fmaf(al[p], wb.y, acc[p][1]);
                acc[p][2] = fmaf(al[p], wb.z, acc[p][2]);
                acc[p][3] = fmaf(al[p], wb.w, acc[p][3]);
            }
            wa = wc; wb = wd;
        }
    }

    // epilogue: + b2 + bd2, coalesced float4 stores
    const float4 v2 = *(const float4*)(b2 + c0);
    const float4 vd = *(const float4*)(bd2 + c0);
    #pragma unroll
    for (int p = 0; p < 8; ++p) {
        float4 o;
        o.x = acc[p][0] + v2.x + vd.x;
        o.y = acc[p][1] + v2.y + vd.y;
        o.z = acc[p][2] + v2.z + vd.z;
        o.w = acc[p][3] + v2.w + vd.w;
        *(float4*)(out + (size_t)(pbase + p0 + p) * HDIM + c0) = o;
    }
}

extern "C" void kernel_launch(void* const* d_in, const int* in_sizes, int n_in,
                              void* d_out, int out_size, void* d_ws, size_t ws_size,
                              hipStream_t stream) {
    const float* xy  = (const float*)d_in[0];
    const float* W1  = (const float*)d_in[1];
    const float* b1  = (const float*)d_in[2];
    const float* W2  = (const float*)d_in[3];
    const float* b2  = (const float*)d_in[4];
    const float* Wd1 = (const float*)d_in[5];
    const float* bd1 = (const float*)d_in[6];
    const float* Wd2 = (const float*)d_in[7];
    const float* bd2 = (const float*)d_in[8];
    // d_in[9] is k == 6 (fixed by setup_inputs; kernels hard-code top-7)
    float* out = (float*)d_out;
    float* md  = (float*)d_ws;  // 16384 floats of scratch for mean distances

    knn_kernel<<<NPTS / 4, 256, 0, stream>>>(xy, md);
    mlp_kernel<<<NPTS / 32, 256, 0, stream>>>(xy, W1, b1, W2, b2,
                                              Wd1, bd1, Wd2, bd2, md, out);
}